// Round 5
// baseline (313.833 us; speedup 1.0000x reference)
//
#include <hip/hip_runtime.h>
#include <hip/hip_bf16.h>
#include <math.h>

#define S_LEN 2048
#define DK 64
#define TQ 16          // queries per block
#define KLW 320        // klocal band width
#define NCH 5          // 5 chunks of 64 keys
#define PSTR 324       // Ps row stride (floats); %32==4 -> conflict-free
#define PSTR4 81

typedef __attribute__((ext_vector_type(8))) short bf16x8;
typedef __attribute__((ext_vector_type(4))) float f32x4;

__device__ __forceinline__ bf16x8 pack8(f32x4 a, f32x4 b) {
    union { __hip_bfloat162 h[4]; bf16x8 v; } u;
    u.h[0] = __float22bfloat162_rn(make_float2(a[0], a[1]));
    u.h[1] = __float22bfloat162_rn(make_float2(a[2], a[3]));
    u.h[2] = __float22bfloat162_rn(make_float2(b[0], b[1]));
    u.h[3] = __float22bfloat162_rn(make_float2(b[2], b[3]));
    return u.v;
}

__global__ __launch_bounds__(256, 4) void band_attn_v5(
    const float* __restrict__ Q,
    const float* __restrict__ K,
    const float* __restrict__ V,
    float* __restrict__ ctx_out,   // [BH, S, DK]
    float* __restrict__ attn_out)  // [BH, S, S]
{
    __shared__ __align__(16) float Ps[TQ * PSTR];   // 20736 B

    const int tid  = threadIdx.x;
    const int bh   = blockIdx.x >> 7;            // 128 tiles per head
    const int q0   = (blockIdx.x & 127) << 4;
    const int base = q0 - 128;                   // kg = base + kl; base % 4 == 0

    const int lane = tid & 63;
    const int wv   = tid >> 6;
    const int col  = lane & 15;
    const int quad = lane >> 4;

    const float* Qh = Q + ((size_t)bh * S_LEN + q0) * DK;
    const float* Kh = K + (size_t)bh * S_LEN * DK;
    const float* Vh = V + (size_t)bh * S_LEN * DK;

    // ---- Q A-frags (pre-scaled by 1/8), loaded once ----
    bf16x8 qf[2];
    #pragma unroll
    for (int h = 0; h < 2; ++h) {
        const float* qp = Qh + (size_t)col * DK + 32 * h + 8 * quad;
        f32x4 a = *(const f32x4*)qp;
        f32x4 b = *(const f32x4*)(qp + 4);
        a *= 0.125f; b *= 0.125f;
        qf[h] = pack8(a, b);
    }

    // ---- score phase: B-frags straight from global K ----
    #pragma unroll
    for (int c = 0; c < NCH; ++c) {
        const int kl  = c * 64 + 16 * wv + col;          // this lane's key (klocal)
        const int kg  = base + kl;
        const int kgc = min(max(kg, 0), S_LEN - 1);      // clamp; mask fixes OOB
        bf16x8 kf[2];
        #pragma unroll
        for (int h = 0; h < 2; ++h) {
            const float* kp = Kh + (size_t)kgc * DK + 32 * h + 8 * quad;
            kf[h] = pack8(*(const f32x4*)kp, *(const f32x4*)(kp + 4));
        }
        f32x4 acc = {0.f, 0.f, 0.f, 0.f};
        acc = __builtin_amdgcn_mfma_f32_16x16x32_bf16(qf[0], kf[0], acc, 0, 0, 0);
        acc = __builtin_amdgcn_mfma_f32_16x16x32_bf16(qf[1], kf[1], acc, 0, 0, 0);
        #pragma unroll
        for (int r = 0; r < 4; ++r) {
            const int qloc = quad * 4 + r;               // C/D: row=(l>>4)*4+reg
            const bool ok = ((unsigned)kg < S_LEN) && (kl > qloc) && (kl <= qloc + 255);
            Ps[qloc * PSTR + kl] = ok ? acc[r] : -INFINITY;
        }
    }
    __syncthreads();

    // ---- softmax: wave wv owns rows 4wv..4wv+3 (320 = 5*64 per row) ----
    #pragma unroll
    for (int rr = 0; rr < 4; ++rr) {
        float* row = Ps + (wv * 4 + rr) * PSTR;
        float v[5];
        #pragma unroll
        for (int j = 0; j < 5; ++j) v[j] = row[lane + 64 * j];
        float m = fmaxf(fmaxf(fmaxf(v[0], v[1]), fmaxf(v[2], v[3])), v[4]);
        #pragma unroll
        for (int off = 32; off > 0; off >>= 1) m = fmaxf(m, __shfl_xor(m, off, 64));
        float e[5], sum = 0.f;
        #pragma unroll
        for (int j = 0; j < 5; ++j) { e[j] = __expf(v[j] - m); sum += e[j]; }
        #pragma unroll
        for (int off = 32; off > 0; off >>= 1) sum += __shfl_xor(sum, off, 64);
        const float inv = 1.0f / sum;
        #pragma unroll
        for (int j = 0; j < 5; ++j) row[lane + 64 * j] = e[j] * inv;
    }
    __syncthreads();   // last barrier; all stores issue after this

    // ---- PV phase: A from Ps (LDS), B straight from global V (d = 16wv+col) ----
    f32x4 o = {0.f, 0.f, 0.f, 0.f};
    const float* vcol = Vh + 16 * wv + col;
    #pragma unroll
    for (int c = 0; c < NCH; ++c) {
        #pragma unroll
        for (int h = 0; h < 2; ++h) {
            const int k0 = base + c * 64 + 32 * h + 8 * quad;
            f32x4 va, vb;
            #pragma unroll
            for (int j = 0; j < 4; ++j) {
                int kgc = min(max(k0 + j, 0), S_LEN - 1);
                va[j] = vcol[(size_t)kgc * DK];
            }
            #pragma unroll
            for (int j = 0; j < 4; ++j) {
                int kgc = min(max(k0 + 4 + j, 0), S_LEN - 1);
                vb[j] = vcol[(size_t)kgc * DK];
            }
            bf16x8 vf = pack8(va, vb);
            const float* pp = Ps + (size_t)col * PSTR + c * 64 + 32 * h + 8 * quad;
            bf16x8 pf = pack8(*(const f32x4*)pp, *(const f32x4*)(pp + 4));
            o = __builtin_amdgcn_mfma_f32_16x16x32_bf16(pf, vf, o, 0, 0, 0);
        }
    }

    // ---- ctx write: q = quad*4+r, d = 16wv+col ----
    {
        float* Cg = ctx_out + ((size_t)bh * S_LEN + q0) * DK;
        #pragma unroll
        for (int r = 0; r < 4; ++r)
            Cg[(size_t)(quad * 4 + r) * DK + 16 * wv + col] = o[r];
    }

    // ---- attn write: uniform band slot range [L,R); no per-slot selects ----
    {
        const int kloff4 = (q0 >> 2) - 32;               // base/4, may be negative
        const int L = max(0, kloff4);
        const int R = min(512, kloff4 + (KLW >> 2));
        f32x4* A4 = (f32x4*)(attn_out + ((size_t)bh * S_LEN + q0 + 4 * wv) * S_LEN);
        const f32x4* Ps4 = (const f32x4*)Ps;
        const f32x4 z = {0.f, 0.f, 0.f, 0.f};
        #pragma unroll
        for (int rr = 0; rr < 4; ++rr) {
            f32x4* row4 = A4 + (size_t)rr * 512;
            const f32x4* pr = Ps4 + (4 * wv + rr) * PSTR4 - kloff4;   // pr[s], s in [L,R)
            for (int s = lane; s < L; s += 64)       row4[s] = z;
            for (int s = L + lane; s < R; s += 64)   row4[s] = pr[s];
            for (int s = R + lane; s < 512; s += 64) row4[s] = z;
        }
    }
}

extern "C" void kernel_launch(void* const* d_in, const int* in_sizes, int n_in,
                              void* d_out, int out_size, void* d_ws, size_t ws_size,
                              hipStream_t stream) {
    const float* Q = (const float*)d_in[0];
    const float* K = (const float*)d_in[1];
    const float* V = (const float*)d_in[2];
    float* out = (float*)d_out;

    const int BH = in_sizes[0] / (S_LEN * DK);          // B*H = 16
    const size_t ctx_elems = (size_t)BH * S_LEN * DK;
    float* ctx  = out;
    float* attn = out + ctx_elems;

    dim3 grid(BH * (S_LEN / TQ));                       // 2048 blocks
    band_attn_v5<<<grid, 256, 0, stream>>>(Q, K, V, ctx, attn);
}

// Round 6
// 302.771 us; speedup vs baseline: 1.0365x; 1.0365x over previous
//
#include <hip/hip_runtime.h>
#include <hip/hip_bf16.h>
#include <math.h>

#define S_LEN 2048
#define DK 64
#define TQ 32          // queries per block
#define KLW 320        // klocal band width
#define NCH 5          // 5 chunks of 64 keys
#define PSTR 324       // Ps row stride (floats); %32==4 -> conflict-free
#define PSTR4 81

typedef __attribute__((ext_vector_type(8))) short bf16x8;
typedef __attribute__((ext_vector_type(4))) float f32x4;

__device__ __forceinline__ bf16x8 pack8(f32x4 a, f32x4 b) {
    union { __hip_bfloat162 h[4]; bf16x8 v; } u;
    u.h[0] = __float22bfloat162_rn(make_float2(a[0], a[1]));
    u.h[1] = __float22bfloat162_rn(make_float2(a[2], a[3]));
    u.h[2] = __float22bfloat162_rn(make_float2(b[0], b[1]));
    u.h[3] = __float22bfloat162_rn(make_float2(b[2], b[3]));
    return u.v;
}

__global__ __launch_bounds__(256, 3) void band_attn_v6(
    const float* __restrict__ Q,
    const float* __restrict__ K,
    const float* __restrict__ V,
    float* __restrict__ ctx_out,   // [BH, S, DK]
    float* __restrict__ attn_out)  // [BH, S, S]
{
    __shared__ __align__(16) float Ps[TQ * PSTR];   // 41472 B -> 3 blocks/CU

    const int tid  = threadIdx.x;
    const int bh   = blockIdx.x >> 6;            // 64 tiles per head
    const int q0   = (blockIdx.x & 63) * TQ;
    const int base = q0 - 128;                   // kg = base + kl; base % 4 == 0

    const int lane = tid & 63;
    const int wv   = tid >> 6;
    const int col  = lane & 15;
    const int quad = lane >> 4;

    const float* Qh = Q + ((size_t)bh * S_LEN + q0) * DK;
    const float* Kh = K + (size_t)bh * S_LEN * DK;
    const float* Vh = V + (size_t)bh * S_LEN * DK;

    // ---- Q A-frags (pre-scaled by 1/8), loaded once ----
    bf16x8 qf[2][2];
    #pragma unroll
    for (int qt = 0; qt < 2; ++qt)
        #pragma unroll
        for (int h = 0; h < 2; ++h) {
            const float* qp = Qh + (size_t)(16 * qt + col) * DK + 32 * h + 8 * quad;
            f32x4 a = *(const f32x4*)qp;
            f32x4 b = *(const f32x4*)(qp + 4);
            a *= 0.125f; b *= 0.125f;
            qf[qt][h] = pack8(a, b);
        }

    // ---- score phase: B-frags straight from global K ----
    #pragma unroll
    for (int c = 0; c < NCH; ++c) {
        const int kl  = c * 64 + 16 * wv + col;          // this lane's key (klocal)
        const int kg  = base + kl;
        const int kgc = min(max(kg, 0), S_LEN - 1);      // clamp; mask fixes OOB
        bf16x8 kf[2];
        #pragma unroll
        for (int h = 0; h < 2; ++h) {
            const float* kp = Kh + (size_t)kgc * DK + 32 * h + 8 * quad;
            kf[h] = pack8(*(const f32x4*)kp, *(const f32x4*)(kp + 4));
        }
        #pragma unroll
        for (int qt = 0; qt < 2; ++qt) {
            f32x4 acc = {0.f, 0.f, 0.f, 0.f};
            acc = __builtin_amdgcn_mfma_f32_16x16x32_bf16(qf[qt][0], kf[0], acc, 0, 0, 0);
            acc = __builtin_amdgcn_mfma_f32_16x16x32_bf16(qf[qt][1], kf[1], acc, 0, 0, 0);
            #pragma unroll
            for (int r = 0; r < 4; ++r) {
                const int qloc = 16 * qt + quad * 4 + r;
                const bool ok = ((unsigned)kg < S_LEN) && (kl > qloc) && (kl <= qloc + 255);
                Ps[qloc * PSTR + kl] = ok ? acc[r] : -INFINITY;
            }
        }
    }

    // ---- EARLY zero stores: band-complement of this wave's 8 attn rows ----
    // Depends on nothing computed; issued before barrier 1 so the HBM write
    // stream starts now and drains while softmax/PV run on other blocks.
    const int kloff4 = (q0 >> 2) - 32;                   // base/4, may be negative
    const int L = max(0, kloff4);
    const int R = min(512, kloff4 + (KLW >> 2));
    f32x4* A4w = (f32x4*)(attn_out + ((size_t)bh * S_LEN + q0 + 8 * wv) * S_LEN);
    {
        const f32x4 z = {0.f, 0.f, 0.f, 0.f};
        #pragma unroll
        for (int rr = 0; rr < 8; ++rr) {
            f32x4* row4 = A4w + (size_t)rr * 512;
            for (int s = lane; s < L; s += 64)       row4[s] = z;
            for (int s = R + lane; s < 512; s += 64) row4[s] = z;
        }
    }
    __syncthreads();

    // ---- softmax: wave wv owns rows 8wv..8wv+7 (320 = 5*64 per row) ----
    #pragma unroll
    for (int rr = 0; rr < 8; ++rr) {
        float* row = Ps + (wv * 8 + rr) * PSTR;
        float v[5];
        #pragma unroll
        for (int j = 0; j < 5; ++j) v[j] = row[lane + 64 * j];
        float m = fmaxf(fmaxf(fmaxf(v[0], v[1]), fmaxf(v[2], v[3])), v[4]);
        #pragma unroll
        for (int off = 32; off > 0; off >>= 1) m = fmaxf(m, __shfl_xor(m, off, 64));
        float e[5], sum = 0.f;
        #pragma unroll
        for (int j = 0; j < 5; ++j) { e[j] = __expf(v[j] - m); sum += e[j]; }
        #pragma unroll
        for (int off = 32; off > 0; off >>= 1) sum += __shfl_xor(sum, off, 64);
        const float inv = 1.0f / sum;
        #pragma unroll
        for (int j = 0; j < 5; ++j) row[lane + 64 * j] = e[j] * inv;
    }
    __syncthreads();   // last barrier; all remaining stores issue after this

    // ---- PV phase: A from Ps (LDS), B straight from global V (d = 16wv+col) ----
    f32x4 o0 = {0.f, 0.f, 0.f, 0.f}, o1 = {0.f, 0.f, 0.f, 0.f};
    const float* vcol = Vh + 16 * wv + col;
    #pragma unroll
    for (int c = 0; c < NCH; ++c) {
        #pragma unroll
        for (int h = 0; h < 2; ++h) {
            const int k0 = base + c * 64 + 32 * h + 8 * quad;
            f32x4 va, vb;
            #pragma unroll
            for (int j = 0; j < 4; ++j) {
                int kgc = min(max(k0 + j, 0), S_LEN - 1);
                va[j] = vcol[(size_t)kgc * DK];
            }
            #pragma unroll
            for (int j = 0; j < 4; ++j) {
                int kgc = min(max(k0 + 4 + j, 0), S_LEN - 1);
                vb[j] = vcol[(size_t)kgc * DK];
            }
            bf16x8 vf = pack8(va, vb);
            #pragma unroll
            for (int qt = 0; qt < 2; ++qt) {
                const float* pp = Ps + (size_t)(16 * qt + col) * PSTR + c * 64 + 32 * h + 8 * quad;
                bf16x8 pf = pack8(*(const f32x4*)pp, *(const f32x4*)(pp + 4));
                if (qt == 0) o0 = __builtin_amdgcn_mfma_f32_16x16x32_bf16(pf, vf, o0, 0, 0, 0);
                else         o1 = __builtin_amdgcn_mfma_f32_16x16x32_bf16(pf, vf, o1, 0, 0, 0);
            }
        }
    }

    // ---- ctx write: q = 16qt + quad*4 + r, d = 16wv + col ----
    {
        float* Cg = ctx_out + ((size_t)bh * S_LEN + q0) * DK;
        #pragma unroll
        for (int r = 0; r < 4; ++r) {
            Cg[(size_t)(quad * 4 + r) * DK + 16 * wv + col]      = o0[r];
            Cg[(size_t)(16 + quad * 4 + r) * DK + 16 * wv + col] = o1[r];
        }
    }

    // ---- band-only attn write: slots [L,R), values from Ps (exact zeros pad) ----
    {
        const f32x4* Ps4 = (const f32x4*)Ps;
        #pragma unroll
        for (int rr = 0; rr < 8; ++rr) {
            f32x4* row4 = A4w + (size_t)rr * 512;
            const f32x4* pr = Ps4 + (8 * wv + rr) * PSTR4 - kloff4;   // pr[s], s in [L,R)
            for (int s = L + lane; s < R; s += 64) row4[s] = pr[s];
        }
    }
}

extern "C" void kernel_launch(void* const* d_in, const int* in_sizes, int n_in,
                              void* d_out, int out_size, void* d_ws, size_t ws_size,
                              hipStream_t stream) {
    const float* Q = (const float*)d_in[0];
    const float* K = (const float*)d_in[1];
    const float* V = (const float*)d_in[2];
    float* out = (float*)d_out;

    const int BH = in_sizes[0] / (S_LEN * DK);          // B*H = 16
    const size_t ctx_elems = (size_t)BH * S_LEN * DK;
    float* ctx  = out;
    float* attn = out + ctx_elems;

    dim3 grid(BH * (S_LEN / TQ));                       // 1024 blocks
    band_attn_v6<<<grid, 256, 0, stream>>>(Q, K, V, ctx, attn);
}

// Round 7
// 298.296 us; speedup vs baseline: 1.0521x; 1.0150x over previous
//
#include <hip/hip_runtime.h>
#include <hip/hip_bf16.h>
#include <math.h>

#define S_LEN 2048
#define DK 64
#define TQ 32          // queries per block
#define KLW 320        // klocal band width
#define NCH 5          // 5 chunks of 64 keys
#define PSTR 324       // Ps row stride (floats); %32==4 -> conflict-free
#define PSTR4 81

typedef __attribute__((ext_vector_type(8))) short bf16x8;
typedef __attribute__((ext_vector_type(4))) float f32x4;

__device__ __forceinline__ bf16x8 pack8(f32x4 a, f32x4 b) {
    union { __hip_bfloat162 h[4]; bf16x8 v; } u;
    u.h[0] = __float22bfloat162_rn(make_float2(a[0], a[1]));
    u.h[1] = __float22bfloat162_rn(make_float2(a[2], a[3]));
    u.h[2] = __float22bfloat162_rn(make_float2(b[0], b[1]));
    u.h[3] = __float22bfloat162_rn(make_float2(b[2], b[3]));
    return u.v;
}

__global__ __launch_bounds__(256, 3) void band_attn_v7(
    const float* __restrict__ Q,
    const float* __restrict__ K,
    const float* __restrict__ V,
    float* __restrict__ ctx_out,   // [BH, S, DK]
    float* __restrict__ attn_out)  // [BH, S, S]
{
    __shared__ __align__(16) float Ps[TQ * PSTR];   // 41472 B -> 3 blocks/CU

    const int tid  = threadIdx.x;
    const int bh   = blockIdx.x >> 6;            // 64 tiles per head
    const int q0   = (blockIdx.x & 63) * TQ;
    const int base = q0 - 128;                   // kg = base + kl; base % 4 == 0
    const int cls  = blockIdx.x & 1;             // phase-skew class

    const int lane = tid & 63;
    const int wv   = tid >> 6;
    const int col  = lane & 15;
    const int quad = lane >> 4;

    const float* Qh = Q + ((size_t)bh * S_LEN + q0) * DK;
    const float* Kh = K + (size_t)bh * S_LEN * DK;
    const float* Vh = V + (size_t)bh * S_LEN * DK;

    // band-complement geometry (f32x4 slot units)
    const int kloff4 = (q0 >> 2) - 32;                   // base/4, may be negative
    const int L = max(0, kloff4);
    const int R = min(512, kloff4 + (KLW >> 2));
    f32x4* A4w = (f32x4*)(attn_out + ((size_t)bh * S_LEN + q0 + 8 * wv) * S_LEN);

    auto store_zeros = [&]() {
        const f32x4 z = {0.f, 0.f, 0.f, 0.f};
        #pragma unroll
        for (int rr = 0; rr < 8; ++rr) {
            f32x4* row4 = A4w + (size_t)rr * 512;
            for (int s = lane; s < L; s += 64)
                __builtin_nontemporal_store(z, row4 + s);
            for (int s = R + lane; s < 512; s += 64)
                __builtin_nontemporal_store(z, row4 + s);
        }
    };

    // ---- Q A-frags (pre-scaled by 1/8), loaded once ----
    bf16x8 qf[2][2];
    #pragma unroll
    for (int qt = 0; qt < 2; ++qt)
        #pragma unroll
        for (int h = 0; h < 2; ++h) {
            const float* qp = Qh + (size_t)(16 * qt + col) * DK + 32 * h + 8 * quad;
            f32x4 a = *(const f32x4*)qp;
            f32x4 b = *(const f32x4*)(qp + 4);
            a *= 0.125f; b *= 0.125f;
            qf[qt][h] = pack8(a, b);
        }

    // ---- score phase: B-frags straight from global K ----
    #pragma unroll
    for (int c = 0; c < NCH; ++c) {
        const int kl  = c * 64 + 16 * wv + col;          // this lane's key (klocal)
        const int kg  = base + kl;
        const int kgc = min(max(kg, 0), S_LEN - 1);      // clamp; mask fixes OOB
        bf16x8 kf[2];
        #pragma unroll
        for (int h = 0; h < 2; ++h) {
            const float* kp = Kh + (size_t)kgc * DK + 32 * h + 8 * quad;
            kf[h] = pack8(*(const f32x4*)kp, *(const f32x4*)(kp + 4));
        }
        #pragma unroll
        for (int qt = 0; qt < 2; ++qt) {
            f32x4 acc = {0.f, 0.f, 0.f, 0.f};
            acc = __builtin_amdgcn_mfma_f32_16x16x32_bf16(qf[qt][0], kf[0], acc, 0, 0, 0);
            acc = __builtin_amdgcn_mfma_f32_16x16x32_bf16(qf[qt][1], kf[1], acc, 0, 0, 0);
            #pragma unroll
            for (int r = 0; r < 4; ++r) {
                const int qloc = 16 * qt + quad * 4 + r;
                const bool ok = ((unsigned)kg < S_LEN) && (kl > qloc) && (kl <= qloc + 255);
                Ps[qloc * PSTR + kl] = ok ? acc[r] : -INFINITY;
            }
        }
    }

    if (cls) store_zeros();     // odd blocks: zeros drain across barrier 1
    __syncthreads();

    // ---- softmax with fused band stores (register-direct, nontemporal) ----
    #pragma unroll
    for (int rr = 0; rr < 8; ++rr) {
        float* row = Ps + (wv * 8 + rr) * PSTR;
        float v[5];
        #pragma unroll
        for (int j = 0; j < 5; ++j) v[j] = row[lane + 64 * j];
        float m = fmaxf(fmaxf(fmaxf(v[0], v[1]), fmaxf(v[2], v[3])), v[4]);
        #pragma unroll
        for (int off = 32; off > 0; off >>= 1) m = fmaxf(m, __shfl_xor(m, off, 64));
        float e[5], sum = 0.f;
        #pragma unroll
        for (int j = 0; j < 5; ++j) { e[j] = __expf(v[j] - m); sum += e[j]; }
        #pragma unroll
        for (int off = 32; off > 0; off >>= 1) sum += __shfl_xor(sum, off, 64);
        const float inv = 1.0f / sum;
        float* arow = attn_out + ((size_t)bh * S_LEN + q0 + 8 * wv + rr) * S_LEN;
        #pragma unroll
        for (int j = 0; j < 5; ++j) {
            const float p = e[j] * inv;          // exact 0 out-of-band
            row[lane + 64 * j] = p;              // write back for PV
            const int kg = base + lane + 64 * j;
            if ((unsigned)kg < S_LEN)
                __builtin_nontemporal_store(p, arow + kg);
        }
    }
    __syncthreads();   // Ps probs visible to all waves (last barrier)

    // ---- PV phase: A from Ps (LDS), B straight from global V (d = 16wv+col) ----
    f32x4 o0 = {0.f, 0.f, 0.f, 0.f}, o1 = {0.f, 0.f, 0.f, 0.f};
    const float* vcol = Vh + 16 * wv + col;
    #pragma unroll
    for (int c = 0; c < NCH; ++c) {
        #pragma unroll
        for (int h = 0; h < 2; ++h) {
            const int k0 = base + c * 64 + 32 * h + 8 * quad;
            f32x4 va, vb;
            #pragma unroll
            for (int j = 0; j < 4; ++j) {
                int kgc = min(max(k0 + j, 0), S_LEN - 1);
                va[j] = vcol[(size_t)kgc * DK];
            }
            #pragma unroll
            for (int j = 0; j < 4; ++j) {
                int kgc = min(max(k0 + 4 + j, 0), S_LEN - 1);
                vb[j] = vcol[(size_t)kgc * DK];
            }
            bf16x8 vf = pack8(va, vb);
            #pragma unroll
            for (int qt = 0; qt < 2; ++qt) {
                const float* pp = Ps + (size_t)(16 * qt + col) * PSTR + c * 64 + 32 * h + 8 * quad;
                bf16x8 pf = pack8(*(const f32x4*)pp, *(const f32x4*)(pp + 4));
                if (qt == 0) o0 = __builtin_amdgcn_mfma_f32_16x16x32_bf16(pf, vf, o0, 0, 0, 0);
                else         o1 = __builtin_amdgcn_mfma_f32_16x16x32_bf16(pf, vf, o1, 0, 0, 0);
            }
        }
    }

    // ---- ctx write: q = 16qt + quad*4 + r, d = 16wv + col ----
    {
        float* Cg = ctx_out + ((size_t)bh * S_LEN + q0) * DK;
        #pragma unroll
        for (int r = 0; r < 4; ++r) {
            Cg[(size_t)(quad * 4 + r) * DK + 16 * wv + col]      = o0[r];
            Cg[(size_t)(16 + quad * 4 + r) * DK + 16 * wv + col] = o1[r];
        }
    }

    if (!cls) store_zeros();    // even blocks: zeros at the end, free-flowing
}

extern "C" void kernel_launch(void* const* d_in, const int* in_sizes, int n_in,
                              void* d_out, int out_size, void* d_ws, size_t ws_size,
                              hipStream_t stream) {
    const float* Q = (const float*)d_in[0];
    const float* K = (const float*)d_in[1];
    const float* V = (const float*)d_in[2];
    float* out = (float*)d_out;

    const int BH = in_sizes[0] / (S_LEN * DK);          // B*H = 16
    const size_t ctx_elems = (size_t)BH * S_LEN * DK;
    float* ctx  = out;
    float* attn = out + ctx_elems;

    dim3 grid(BH * (S_LEN / TQ));                       // 1024 blocks
    band_attn_v7<<<grid, 256, 0, stream>>>(Q, K, V, ctx, attn);
}